// Round 9
// baseline (186.830 us; speedup 1.0000x reference)
//
#include <hip/hip_runtime.h>
#include <hip/hip_fp16.h>
#include <math.h>

// Caps1D dynamic routing — coalesced fp16 W, LDS-resident u_ji, 1024-thr blocks.
//
// u: [B=1024, R=2336, M=4] fp32 ; W: [K=2, R=2336, M=4, P=16] fp32
// out[b,k] = norm/(1+norm) of final squashed routing sum.
//
// Round-8 result: W-transpose prepass (fp16 [k][m][r][p]) fixed the build's
// uncoalesced loads (steady 162 -> 112 us, VALUBusy 19 -> 41%). Remaining
// regime: latency-bound at 4 waves/SIMD (LDS 75KB -> 2 blocks/CU of 512 thr).
// Round-8 kernel used only 60 VGPRs — it FITS the 64-VGPR cap that 1024-thr
// workgroups get (measured r2-r4). So: 1024 threads/block, same 75KB LDS ->
// 2 blocks/CU = 8 waves/SIMD (2x latency hiding), half the per-wave work
// (build 37->19 steps, sweep 10->5), half the sequential blocks per CU.

#define THREADS 1024
#define NWAVE 16
#define RR 2336
#define KK 2

// ---- prepass: W fp32 [k][r][m][p] -> fp16 [k][m][r][p2 half2] ----
__global__ __launch_bounds__(256)
void w_to_fp16_kernel(const float* __restrict__ W, __half2* __restrict__ Wh2)
{
    const int n2 = KK * 4 * RR * 8;              // 149504 half2
    for (int j2 = blockIdx.x * 256 + threadIdx.x; j2 < n2; j2 += gridDim.x * 256) {
        const int k   = j2 / (4 * RR * 8);
        int rem       = j2 - k * (4 * RR * 8);
        const int m   = rem / (RR * 8);
        rem          -= m * (RR * 8);
        const int r   = rem >> 3;
        const int p2  = rem & 7;
        const float2 f = *(const float2*)(W + (((size_t)(k * RR + r) * 4 + m) * 16 + p2 * 2));
        Wh2[j2] = __floats2half2_rn(f.x, f.y);
    }
}

__global__ __launch_bounds__(THREADS)
void caps_routing_kernel(const float* __restrict__ u,
                         const __half2* __restrict__ Wh2,
                         float* __restrict__ out)
{
    extern __shared__ char smem[];
    __half* uji  = (__half*)smem;                    // RR*16 halves = 74752 B
    float*  red  = (float*)(smem + RR * 32);         // [NWAVE][17]
    float*  vbuf = red + NWAVE * 17;                 // [16] cumulative v

    const int bi   = blockIdx.x;                     // 2048 blocks
    const int b    = bi >> 1;
    const int k    = bi & 1;
    const int tid  = threadIdx.x;
    const int lane = tid & 63;
    const int wave = tid >> 6;                       // 0..15
    const int p2   = lane & 7;                       // half2 column 0..7
    const int g    = lane >> 3;                      // row-in-group 0..7

    const float4* __restrict__ u4p = (const float4*)u;

    // ---- build u_ji (fp16 -> LDS) + iteration-0 accumulation (e == 1) ----
    // W fp16 layout: Wh2[((k*4+m)*RR + r)*8 + p2]; per-m wave load = 64
    // consecutive half2 (256 B, 4 lines, minimal).
    const __half2* __restrict__ wb = Wh2 + (size_t)(k * 4) * RR * 8 + p2;
    float sA = 0.0f, sB = 0.0f;
    #pragma unroll 2
    for (int i = 0; i < 19; ++i) {                   // 19*128 = 2432 >= 2336
        const int r0 = i * 128 + wave * 8 + g;
        const bool ok = r0 < RR;
        const int r  = ok ? r0 : RR - 1;             // clamp loads, mask effects
        float4 uu = u4p[b * RR + r];
        float2 w0 = __half22float2(wb[(size_t)(0 * RR + r) * 8]);
        float2 w1 = __half22float2(wb[(size_t)(1 * RR + r) * 8]);
        float2 w2 = __half22float2(wb[(size_t)(2 * RR + r) * 8]);
        float2 w3 = __half22float2(wb[(size_t)(3 * RR + r) * 8]);
        float ax = uu.x * w0.x + uu.y * w1.x + uu.z * w2.x + uu.w * w3.x;
        float ay = uu.x * w0.y + uu.y * w1.y + uu.z * w2.y + uu.w * w3.y;
        if (ok) {
            sA += ax; sB += ay;
            *(__half2*)(uji + r * 16 + p2 * 2) = __floats2half2_rn(ax, ay);
        }
    }
    // reduce iter-0 sums over g (xor 8/16/32 preserves p2)
    sA += __shfl_xor(sA, 8);  sB += __shfl_xor(sB, 8);
    sA += __shfl_xor(sA, 16); sB += __shfl_xor(sB, 16);
    sA += __shfl_xor(sA, 32); sB += __shfl_xor(sB, 32);
    if (lane < 8) {
        red[wave * 17 + 2 * p2]     = sA;
        red[wave * 17 + 2 * p2 + 1] = sB;
    }
    __syncthreads();

    // iteration-0 squash: se == R exactly (uniform softmax)
    if (wave == 0 && lane < 16) {
        float col = red[lane];
        #pragma unroll
        for (int w = 1; w < NWAVE; ++w) col += red[w * 17 + lane];
        float nr = col * col;
        nr += __shfl_xor(nr, 1);
        nr += __shfl_xor(nr, 2);
        nr += __shfl_xor(nr, 4);
        nr += __shfl_xor(nr, 8);
        const float inv  = 1.0f / (float)RR;
        const float norm = nr * inv * inv;
        const float f    = sqrtf(norm) / (1.0f + norm);
        vbuf[lane] = col * inv * f;                  // v0
    }
    __syncthreads();

    // ---- routing iterations 1,2: one LDS sweep each ----
    #pragma unroll 1
    for (int it = 1; it < 3; ++it) {
        float vpart[8];
        #pragma unroll
        for (int i = 0; i < 8; ++i) vpart[i] = vbuf[(lane & 1) * 8 + i];

        // issue all 5 row-loads up front (ILP over LDS latency)
        float4 raw[5];
        #pragma unroll
        for (int s = 0; s < 5; ++s) {                // 5*512 = 2560 >= 2336
            int row = s * 512 + wave * 32 + (lane >> 1);
            row = (row < RR) ? row : (RR - 1);
            raw[s] = *(const float4*)((const char*)uji + row * 32 + (lane & 1) * 16);
        }

        float s8[8] = {0,0,0,0,0,0,0,0};
        float se = 0.0f;
        #pragma unroll
        for (int s = 0; s < 5; ++s) {
            const bool ok = (s * 512 + wave * 32 + (lane >> 1)) < RR;
            const __half2* hp = (const __half2*)&raw[s];
            float h[8];
            #pragma unroll
            for (int q = 0; q < 4; ++q) {
                float2 f = __half22float2(hp[q]);
                h[2*q] = f.x; h[2*q+1] = f.y;
            }
            float d = 0.0f;
            #pragma unroll
            for (int i = 0; i < 8; ++i) d += h[i] * vpart[i];
            d += __shfl_xor(d, 1);                   // join the two half-dots
            float e = ok ? __expf(d) : 0.0f;         // no max-subtract (bounded)
            se += e;
            #pragma unroll
            for (int i = 0; i < 8; ++i) s8[i] += e * h[i];
        }

        // parity-preserving xor reduction (offsets 2..32 keep lane bit0)
        #pragma unroll
        for (int o = 2; o <= 32; o <<= 1) {
            se += __shfl_xor(se, o);
            #pragma unroll
            for (int i = 0; i < 8; ++i) s8[i] += __shfl_xor(s8[i], o);
        }
        if (lane < 2) {
            #pragma unroll
            for (int i = 0; i < 8; ++i) red[wave * 17 + (lane & 1) * 8 + i] = s8[i];
            if (lane == 0) red[wave * 17 + 16] = se;
        }
        __syncthreads();

        if (wave == 0 && lane < 17) {
            float col = red[lane];
            #pragma unroll
            for (int w = 1; w < NWAVE; ++w) col += red[w * 17 + lane];
            float se_t = __shfl(col, 16);
            if (lane < 16) {
                float nr = col * col;
                nr += __shfl_xor(nr, 1);
                nr += __shfl_xor(nr, 2);
                nr += __shfl_xor(nr, 4);
                nr += __shfl_xor(nr, 8);
                float inv  = 1.0f / se_t;
                float norm = nr * inv * inv;
                float f    = sqrtf(norm) / (1.0f + norm);
                float vnew = col * inv * f;
                if (it == 1) vbuf[lane] += vnew;     // cumulative V
                else if (lane == 0) out[b * KK + k] = norm / (1.0f + norm);
            }
        }
        __syncthreads();
    }
}

extern "C" void kernel_launch(void* const* d_in, const int* in_sizes, int n_in,
                              void* d_out, int out_size, void* d_ws, size_t ws_size,
                              hipStream_t stream) {
    const float* u = (const float*)d_in[0];   // [1024, 2336, 4]
    const float* W = (const float*)d_in[1];   // [2, 2336, 4, 16]
    float* out = (float*)d_out;               // [1024, 2]
    __half2* Wh2 = (__half2*)d_ws;            // 299008 B of scratch

    w_to_fp16_kernel<<<dim3(256), dim3(256), 0, stream>>>(W, Wh2);

    const size_t lds_bytes = RR * 32 + (NWAVE * 17 + 16) * sizeof(float); // 75904
    caps_routing_kernel<<<dim3(2048), dim3(THREADS), lds_bytes, stream>>>(u, Wh2, out);
}

// Round 10
// 139.389 us; speedup vs baseline: 1.3404x; 1.3404x over previous
//
#include <hip/hip_runtime.h>
#include <hip/hip_fp16.h>
#include <math.h>

// Caps1D dynamic routing — fp16 W re-laid [k][r][p2][m], LDS u_ji, 512-thr.
//
// u: [B=1024, R=2336, M=4] fp32 ; W: [K=2, R=2336, M=4, P=16] fp32
// out[b,k] = norm/(1+norm) of final squashed routing sum.
//
// Measured lessons driving this version:
//  r2/r3/r4/r9: 1024-thr workgroups have a HARD 64-VGPR cap -> either spills
//    or load-serialization (r9: VGPR 36, dur regressed 112->137). Use 512 thr
//    with launch_bounds(512,2) -> 128-VGPR budget (measured).
//  r7->r8: W-load coalescing was 85% of runtime; fp16 transposed W fixed it.
//    Now go further: layout [k][r][p2][m] makes each row's W ONE 16B load
//    (was 4 scattered b32), and the build is software-pipelined (explicit
//    next-step prefetch regs) to hide ~200cyc L2 latency.
//  r6-r8: 6 barriers/block with wave0-only squash idled 7 waves. Distributed
//    squash: every wave redundantly reduces red[] and carries vcum in regs;
//    red[] is double-buffered; 3 barriers total, no vbuf.

#define THREADS 512
#define NWAVE 8
#define RR 2336
#define KK 2

// ---- prepass: W fp32 [k][r][m][p] -> fp16 [k][r][p2][m]  (half2 m-pairs) ----
// Output half2 index: ((k*RR + r)*8 + p2)*4 + mh   (mh = m-pair 0..3? no: m)
// We store per (r,p2) the 8 halves {m0:(p,p+1), m1:(p,p+1), m2, m3} as 4 half2:
//   half2[m] = ( W[k,r,m,2*p2], W[k,r,m,2*p2+1] )
__global__ __launch_bounds__(256)
void w_repack_kernel(const float* __restrict__ W, __half2* __restrict__ Wt)
{
    const int n2 = KK * RR * 8 * 4;              // 149504 half2
    for (int j2 = blockIdx.x * 256 + threadIdx.x; j2 < n2; j2 += gridDim.x * 256) {
        const int m   = j2 & 3;
        const int p2  = (j2 >> 2) & 7;
        const int rk  = j2 >> 5;                 // k*RR + r
        const float2 f = *(const float2*)(W + ((size_t)rk * 4 + m) * 16 + p2 * 2);
        Wt[j2] = __floats2half2_rn(f.x, f.y);
    }
}

__global__ __launch_bounds__(THREADS, 2)
void caps_routing_kernel(const float* __restrict__ u,
                         const __half2* __restrict__ Wt,
                         float* __restrict__ out)
{
    __shared__ __half uji[RR * 16];              // 74752 B
    __shared__ float  red[2][NWAVE][17];         // double-buffered partials

    const int bi   = blockIdx.x;                 // 2048 blocks
    const int b    = bi >> 1;
    const int k    = bi & 1;
    const int tid  = threadIdx.x;
    const int lane = tid & 63;
    const int wave = tid >> 6;
    const int p2   = lane & 7;                   // half2 column pair 0..7
    const int g    = lane >> 3;                  // row-in-group 0..7

    const float4* __restrict__ u4p = (const float4*)u;
    // per-(r,p2) W record = 4 half2 = one float4
    const float4* __restrict__ w4t = (const float4*)Wt + (size_t)k * RR * 8 + p2;

    // ---- build u_ji (fp16 -> LDS) + iter-0 sums, software-pipelined ----
    float sA = 0.0f, sB = 0.0f;
    {
        int r0 = wave * 8 + g;                   // step-0 row (always < RR)
        float4 uu_n = u4p[b * RR + r0];
        float4 wv_n = w4t[(size_t)r0 * 8];
        #pragma unroll 4
        for (int i = 0; i < 37; ++i) {           // 37*64 = 2368 >= 2336
            const float4 uu = uu_n;
            const float4 wv = wv_n;
            const int r = i * 64 + wave * 8 + g;
            if (i + 1 < 37) {                    // prefetch next step
                int rn = (i + 1) * 64 + wave * 8 + g;
                rn = (rn < RR) ? rn : (RR - 1);
                uu_n = u4p[b * RR + rn];
                wv_n = w4t[(size_t)rn * 8];
            }
            const __half2* hm = (const __half2*)&wv;
            float2 m0 = __half22float2(hm[0]);
            float2 m1 = __half22float2(hm[1]);
            float2 m2 = __half22float2(hm[2]);
            float2 m3 = __half22float2(hm[3]);
            float ax = uu.x * m0.x + uu.y * m1.x + uu.z * m2.x + uu.w * m3.x;
            float ay = uu.x * m0.y + uu.y * m1.y + uu.z * m2.y + uu.w * m3.y;
            if (r < RR) {
                sA += ax; sB += ay;
                *(__half2*)(uji + r * 16 + p2 * 2) = __floats2half2_rn(ax, ay);
            }
        }
    }
    // iter-0 partials: reduce over g (xor 8/16/32 preserves p2)
    sA += __shfl_xor(sA, 8);  sB += __shfl_xor(sB, 8);
    sA += __shfl_xor(sA, 16); sB += __shfl_xor(sB, 16);
    sA += __shfl_xor(sA, 32); sB += __shfl_xor(sB, 32);
    if (lane < 8) {
        red[0][wave][2 * p2]     = sA;
        red[0][wave][2 * p2 + 1] = sB;
    }
    __syncthreads();                             // barrier 1: uji + red[0] ready

    float vcum[8];                               // this lane's v[(lane&1)*8+i]

    // ---- distributed squash, iter 0 (se == RR exactly) ----
    {
        float col = 0.0f;
        if (lane < 16) {
            #pragma unroll
            for (int w = 0; w < NWAVE; ++w) col += red[0][w][lane];
        }
        float nr = col * col;                    // butterfly within 16-groups
        nr += __shfl_xor(nr, 1);
        nr += __shfl_xor(nr, 2);
        nr += __shfl_xor(nr, 4);
        nr += __shfl_xor(nr, 8);
        const float inv  = 1.0f / (float)RR;
        const float norm = nr * inv * inv;
        const float f    = sqrtf(norm) / (1.0f + norm);
        const float vnew = col * inv * f;        // valid in lanes 0..15
        #pragma unroll
        for (int i = 0; i < 8; ++i) vcum[i] = __shfl(vnew, (lane & 1) * 8 + i);
    }

    // ---- iterations 1,2: sweep + distributed squash ----
    #pragma unroll 1
    for (int it = 1; it < 3; ++it) {
        const int buf = it & 1;                  // 1 then 0 (0 free after it0 read)

        // issue all 10 row-loads up front (ILP over LDS latency)
        float4 raw[10];
        #pragma unroll
        for (int s = 0; s < 10; ++s) {
            int row = s * 256 + wave * 32 + (lane >> 1);
            row = (row < RR) ? row : (RR - 1);
            raw[s] = *(const float4*)((const char*)uji + row * 32 + (lane & 1) * 16);
        }

        float s8[8] = {0,0,0,0,0,0,0,0};
        float se = 0.0f;
        #pragma unroll
        for (int s = 0; s < 10; ++s) {
            const bool ok = (s * 256 + wave * 32 + (lane >> 1)) < RR;
            const __half2* hp = (const __half2*)&raw[s];
            float h[8];
            #pragma unroll
            for (int q = 0; q < 4; ++q) {
                float2 f = __half22float2(hp[q]);
                h[2*q] = f.x; h[2*q+1] = f.y;
            }
            float d = 0.0f;
            #pragma unroll
            for (int i = 0; i < 8; ++i) d += h[i] * vcum[i];
            d += __shfl_xor(d, 1);               // join the two half-dots
            float e = ok ? __expf(d) : 0.0f;     // no max-subtract (bounded)
            se += e;
            #pragma unroll
            for (int i = 0; i < 8; ++i) s8[i] += e * h[i];
        }

        // parity-preserving xor reduction (offsets 2..32 keep lane bit0)
        #pragma unroll
        for (int o = 2; o <= 32; o <<= 1) {
            se += __shfl_xor(se, o);
            #pragma unroll
            for (int i = 0; i < 8; ++i) s8[i] += __shfl_xor(s8[i], o);
        }
        if (lane < 2) {
            #pragma unroll
            for (int i = 0; i < 8; ++i) red[buf][wave][(lane & 1) * 8 + i] = s8[i];
            if (lane == 0) red[buf][wave][16] = se;
        }
        __syncthreads();                         // barrier 2 / 3

        // distributed squash from red[buf]
        {
            float col = 0.0f;
            if (lane < 17) {
                #pragma unroll
                for (int w = 0; w < NWAVE; ++w) col += red[buf][w][lane];
            }
            float nr = col * col;
            nr += __shfl_xor(nr, 1);
            nr += __shfl_xor(nr, 2);
            nr += __shfl_xor(nr, 4);
            nr += __shfl_xor(nr, 8);
            const float se_t = __shfl(col, 16);  // lane 16 carried sum(e)
            const float inv  = 1.0f / se_t;
            const float norm = nr * inv * inv;
            if (it == 1) {
                const float f    = sqrtf(norm) / (1.0f + norm);
                const float vnew = col * inv * f;
                #pragma unroll
                for (int i = 0; i < 8; ++i) vcum[i] += __shfl(vnew, (lane & 1) * 8 + i);
            } else if (wave == 0 && lane == 0) {
                out[b * KK + k] = norm / (1.0f + norm);
            }
        }
    }
}

extern "C" void kernel_launch(void* const* d_in, const int* in_sizes, int n_in,
                              void* d_out, int out_size, void* d_ws, size_t ws_size,
                              hipStream_t stream) {
    const float* u = (const float*)d_in[0];   // [1024, 2336, 4]
    const float* W = (const float*)d_in[1];   // [2, 2336, 4, 16]
    float* out = (float*)d_out;               // [1024, 2]
    __half2* Wt = (__half2*)d_ws;             // 299008 B of scratch

    w_repack_kernel<<<dim3(256), dim3(256), 0, stream>>>(W, Wt);
    caps_routing_kernel<<<dim3(2048), dim3(THREADS), 0, stream>>>(u, Wt, out);
}

// Round 11
// 137.155 us; speedup vs baseline: 1.3622x; 1.0163x over previous
//
#include <hip/hip_runtime.h>
#include <hip/hip_fp16.h>
#include <math.h>

// Caps1D dynamic routing — fp16 W [k][r][p2][m], LDS u_ji, 512-thr,
// chunk-4 double-buffered build pipeline + fdot2 sweep.
//
// u: [B=1024, R=2336, M=4] fp32 ; W: [K=2, R=2336, M=4, P=16] fp32
// out[b,k] = norm/(1+norm) of final squashed routing sum.
//
// Measured history: r7 coalescing diagnosis (85% of cycles were W cache-line
// transactions) -> fp16 transposed W. r9: 1024-thr blocks have a hard 64-VGPR
// cap -> stay at 512 thr / launch_bounds(512,2) = 128 VGPR. r10: pipelined
// build + distributed squash -> 85us steady, VALUBusy 58%, VGPR 60.
// r11: VGPR headroom (60 of 128) -> chunk-4 double-buffered build (8 loads
// in flight vs 2); v_dot2_f32_f16 for the sweep's logit dot (cuts 8 cvt +
// 8 fma to 4 dot2 per step).

#define THREADS 512
#define NWAVE 8
#define RR 2336
#define KK 2

#if __has_builtin(__builtin_amdgcn_fdot2)
typedef _Float16 h2v __attribute__((ext_vector_type(2)));
static __device__ __forceinline__ float dot2h(__half2 a, __half2 b, float c) {
    h2v av, bv;
    __builtin_memcpy(&av, &a, 4);
    __builtin_memcpy(&bv, &b, 4);
    return __builtin_amdgcn_fdot2(av, bv, c, false);
}
#else
static __device__ __forceinline__ float dot2h(__half2 a, __half2 b, float c) {
    float2 fa = __half22float2(a), fb = __half22float2(b);
    return fmaf(fa.x, fb.x, fmaf(fa.y, fb.y, c));
}
#endif

// ---- prepass: W fp32 [k][r][m][p] -> fp16 [k][r][p2][m] (4 half2 / rec) ----
__global__ __launch_bounds__(256)
void w_repack_kernel(const float* __restrict__ W, __half2* __restrict__ Wt)
{
    const int n2 = KK * RR * 8 * 4;              // 149504 half2
    for (int j2 = blockIdx.x * 256 + threadIdx.x; j2 < n2; j2 += gridDim.x * 256) {
        const int m   = j2 & 3;
        const int p2  = (j2 >> 2) & 7;
        const int rk  = j2 >> 5;                 // k*RR + r
        const float2 f = *(const float2*)(W + ((size_t)rk * 4 + m) * 16 + p2 * 2);
        Wt[j2] = __floats2half2_rn(f.x, f.y);
    }
}

// load 4 build steps (chunk c) into register buffers
#define LOAD_CHUNK(c, uu, wv)                                          \
    {                                                                  \
        _Pragma("unroll")                                              \
        for (int q = 0; q < 4; ++q) {                                  \
            int r = (c) * 256 + q * 64 + wave * 8 + g;                 \
            r = (r < RR) ? r : (RR - 1);                               \
            uu[q] = u4p[b * RR + r];                                   \
            wv[q] = w4t[(size_t)r * 8];                                \
        }                                                              \
    }

// compute 4 build steps from buffered registers
#define COMP_CHUNK(c, uu, wv)                                          \
    {                                                                  \
        _Pragma("unroll")                                              \
        for (int q = 0; q < 4; ++q) {                                  \
            const int r = (c) * 256 + q * 64 + wave * 8 + g;           \
            const __half2* hm = (const __half2*)&wv[q];                \
            float2 m0 = __half22float2(hm[0]);                         \
            float2 m1 = __half22float2(hm[1]);                         \
            float2 m2 = __half22float2(hm[2]);                         \
            float2 m3 = __half22float2(hm[3]);                         \
            float ax = uu[q].x * m0.x + uu[q].y * m1.x                 \
                     + uu[q].z * m2.x + uu[q].w * m3.x;                \
            float ay = uu[q].x * m0.y + uu[q].y * m1.y                 \
                     + uu[q].z * m2.y + uu[q].w * m3.y;                \
            if (r < RR) {                                              \
                sA += ax; sB += ay;                                    \
                *(__half2*)(uji + r * 16 + p2 * 2) =                   \
                    __floats2half2_rn(ax, ay);                         \
            }                                                          \
        }                                                              \
    }

__global__ __launch_bounds__(THREADS, 2)
void caps_routing_kernel(const float* __restrict__ u,
                         const __half2* __restrict__ Wt,
                         float* __restrict__ out)
{
    __shared__ __half uji[RR * 16];              // 74752 B
    __shared__ float  red[2][NWAVE][17];         // double-buffered partials

    const int bi   = blockIdx.x;                 // 2048 blocks
    const int b    = bi >> 1;
    const int k    = bi & 1;
    const int tid  = threadIdx.x;
    const int lane = tid & 63;
    const int wave = tid >> 6;
    const int p2   = lane & 7;                   // half2 column pair 0..7
    const int g    = lane >> 3;                  // row-in-group 0..7

    const float4* __restrict__ u4p = (const float4*)u;
    const float4* __restrict__ w4t = (const float4*)Wt + (size_t)k * RR * 8 + p2;

    // ---- build u_ji (fp16 -> LDS) + iter-0 sums; chunk-4 double-buffered ----
    float sA = 0.0f, sB = 0.0f;
    {
        float4 uuA[4], wvA[4], uuB[4], wvB[4];
        LOAD_CHUNK(0, uuA, wvA)
        #pragma unroll
        for (int c = 0; c < 10; c += 2) {        // 10 chunks * 256 rows = 2560
            if (c + 1 < 10) LOAD_CHUNK(c + 1, uuB, wvB)
            COMP_CHUNK(c, uuA, wvA)
            if (c + 2 < 10) LOAD_CHUNK(c + 2, uuA, wvA)
            if (c + 1 < 10) COMP_CHUNK(c + 1, uuB, wvB)
        }
    }
    // iter-0 partials: reduce over g (xor 8/16/32 preserves p2)
    sA += __shfl_xor(sA, 8);  sB += __shfl_xor(sB, 8);
    sA += __shfl_xor(sA, 16); sB += __shfl_xor(sB, 16);
    sA += __shfl_xor(sA, 32); sB += __shfl_xor(sB, 32);
    if (lane < 8) {
        red[0][wave][2 * p2]     = sA;
        red[0][wave][2 * p2 + 1] = sB;
    }
    __syncthreads();                             // barrier 1: uji + red[0] ready

    float vcum[8];                               // this lane's v[(lane&1)*8+i]

    // ---- distributed squash, iter 0 (se == RR exactly) ----
    {
        float col = 0.0f;
        if (lane < 16) {
            #pragma unroll
            for (int w = 0; w < NWAVE; ++w) col += red[0][w][lane];
        }
        float nr = col * col;
        nr += __shfl_xor(nr, 1);
        nr += __shfl_xor(nr, 2);
        nr += __shfl_xor(nr, 4);
        nr += __shfl_xor(nr, 8);
        const float inv  = 1.0f / (float)RR;
        const float norm = nr * inv * inv;
        const float f    = sqrtf(norm) / (1.0f + norm);
        const float vnew = col * inv * f;        // valid in lanes 0..15
        #pragma unroll
        for (int i = 0; i < 8; ++i) vcum[i] = __shfl(vnew, (lane & 1) * 8 + i);
    }

    // ---- iterations 1,2: sweep + distributed squash ----
    #pragma unroll 1
    for (int it = 1; it < 3; ++it) {
        const int buf = it & 1;

        // pack this lane's v-half to half2 for dot2
        __half2 v2[4];
        #pragma unroll
        for (int i = 0; i < 4; ++i) v2[i] = __floats2half2_rn(vcum[2*i], vcum[2*i+1]);

        // issue all 10 row-loads up front (ILP over LDS latency)
        float4 raw[10];
        #pragma unroll
        for (int s = 0; s < 10; ++s) {
            int row = s * 256 + wave * 32 + (lane >> 1);
            row = (row < RR) ? row : (RR - 1);
            raw[s] = *(const float4*)((const char*)uji + row * 32 + (lane & 1) * 16);
        }

        float s8[8] = {0,0,0,0,0,0,0,0};
        float se = 0.0f;
        #pragma unroll
        for (int s = 0; s < 10; ++s) {
            const bool ok = (s * 256 + wave * 32 + (lane >> 1)) < RR;
            const __half2* hp = (const __half2*)&raw[s];
            // logit half-dot via v_dot2_f32_f16 (fp16 x fp16 -> fp32 acc)
            float d = dot2h(hp[0], v2[0],
                      dot2h(hp[1], v2[1],
                      dot2h(hp[2], v2[2],
                      dot2h(hp[3], v2[3], 0.0f))));
            d += __shfl_xor(d, 1);               // join the two half-dots
            float e = ok ? __expf(d) : 0.0f;     // no max-subtract (bounded)
            se += e;
            #pragma unroll
            for (int q = 0; q < 4; ++q) {
                float2 f = __half22float2(hp[q]);
                s8[2*q]   = fmaf(f.x, e, s8[2*q]);
                s8[2*q+1] = fmaf(f.y, e, s8[2*q+1]);
            }
        }

        // parity-preserving xor reduction (offsets 2..32 keep lane bit0)
        #pragma unroll
        for (int o = 2; o <= 32; o <<= 1) {
            se += __shfl_xor(se, o);
            #pragma unroll
            for (int i = 0; i < 8; ++i) s8[i] += __shfl_xor(s8[i], o);
        }
        if (lane < 2) {
            #pragma unroll
            for (int i = 0; i < 8; ++i) red[buf][wave][(lane & 1) * 8 + i] = s8[i];
            if (lane == 0) red[buf][wave][16] = se;
        }
        __syncthreads();                         // barrier 2 / 3

        // distributed squash from red[buf]
        {
            float col = 0.0f;
            if (lane < 17) {
                #pragma unroll
                for (int w = 0; w < NWAVE; ++w) col += red[buf][w][lane];
            }
            float nr = col * col;
            nr += __shfl_xor(nr, 1);
            nr += __shfl_xor(nr, 2);
            nr += __shfl_xor(nr, 4);
            nr += __shfl_xor(nr, 8);
            const float se_t = __shfl(col, 16);  // lane 16 carried sum(e)
            const float inv  = 1.0f / se_t;
            const float norm = nr * inv * inv;
            if (it == 1) {
                const float f    = sqrtf(norm) / (1.0f + norm);
                const float vnew = col * inv * f;
                #pragma unroll
                for (int i = 0; i < 8; ++i) vcum[i] += __shfl(vnew, (lane & 1) * 8 + i);
            } else if (wave == 0 && lane == 0) {
                out[b * KK + k] = norm / (1.0f + norm);
            }
        }
    }
}

extern "C" void kernel_launch(void* const* d_in, const int* in_sizes, int n_in,
                              void* d_out, int out_size, void* d_ws, size_t ws_size,
                              hipStream_t stream) {
    const float* u = (const float*)d_in[0];   // [1024, 2336, 4]
    const float* W = (const float*)d_in[1];   // [2, 2336, 4, 16]
    float* out = (float*)d_out;               // [1024, 2]
    __half2* Wt = (__half2*)d_ws;             // 299008 B of scratch

    w_repack_kernel<<<dim3(256), dim3(256), 0, stream>>>(W, Wt);
    caps_routing_kernel<<<dim3(2048), dim3(THREADS), 0, stream>>>(u, Wt, out);
}